// Round 2
// baseline (2811.964 us; speedup 1.0000x reference)
//
#include <hip/hip_runtime.h>
#include <hip/hip_bf16.h>

typedef __attribute__((ext_vector_type(8))) short short8;
typedef __attribute__((ext_vector_type(4))) float floatx4;
typedef unsigned short ushort_t;

__device__ inline float b2f(ushort_t s) {
    return __uint_as_float(((unsigned int)s) << 16);
}
__device__ inline ushort_t f2b(float f) {
    unsigned int u = __float_as_uint(f);
    unsigned int r = 0x7fff + ((u >> 16) & 1);
    return (ushort_t)((u + r) >> 16);
}
__device__ inline void load8(const ushort_t* p, float* f) {
    uint4 v = *(const uint4*)p;
    const ushort_t* e = (const ushort_t*)&v;
#pragma unroll
    for (int i = 0; i < 8; ++i) f[i] = b2f(e[i]);
}
__device__ inline void load8(const float* p, float* f) {
    float4 a = *(const float4*)p;
    float4 b = *(const float4*)(p + 4);
    f[0] = a.x; f[1] = a.y; f[2] = a.z; f[3] = a.w;
    f[4] = b.x; f[5] = b.y; f[6] = b.z; f[7] = b.w;
}

// ---------------- RMSNorm: fp32 in -> bf16 out. one block per row, D=2048 ----------------
__global__ __launch_bounds__(256) void rmsnorm_kernel(const float* __restrict__ x,
                                                      const float* __restrict__ w,
                                                      ushort_t* __restrict__ out, int D) {
    int row = blockIdx.x;
    int t = threadIdx.x;
    const float* xr = x + (size_t)row * D;
    float f[8];
    load8(xr + t * 8, f);
    float ss = 0.f;
#pragma unroll
    for (int i = 0; i < 8; ++i) ss += f[i] * f[i];
#pragma unroll
    for (int m = 1; m < 64; m <<= 1) ss += __shfl_xor(ss, m);
    __shared__ float wsum[4];
    if ((t & 63) == 0) wsum[t >> 6] = ss;
    __syncthreads();
    float tot = wsum[0] + wsum[1] + wsum[2] + wsum[3];
    float r = rsqrtf(tot / (float)D + 1e-6f);
    float wf[8];
    load8(w + t * 8, wf);
    ushort_t o[8];
#pragma unroll
    for (int i = 0; i < 8; ++i) o[i] = f2b(f[i] * r * wf[i]);
    *(uint4*)(out + (size_t)row * D + t * 8) = *(const uint4*)o;
}

// ---------------- bf16 GEMM: C[M,N] = A[M,K](bf16) * B[K,N](fp32 weights) ----------------
// MODE 0: C = AB ; MODE 1: C = AB + AUX ; MODE 2: C = silu(AUX) * AB
// AUXF: AUX is fp32; OUTF: C is fp32
#define BM 128
#define BN 128
#define BKK 32

template <int MODE, bool AUXF, bool OUTF>
__global__ __launch_bounds__(256, 2) void gemm_kernel(const ushort_t* __restrict__ A,
                                                      const float* __restrict__ B,
                                                      const void* __restrict__ AUXv,
                                                      void* __restrict__ Cv,
                                                      int M, int N, int K) {
    __shared__ __align__(16) ushort_t As[BM][BKK + 8];   // [row][k]
    __shared__ __align__(16) ushort_t Bs[BN][BKK + 8];   // transposed: [n][k]
    int t = threadIdx.x;
    int bm = blockIdx.x * BM;
    int bn = blockIdx.y * BN;
    int wave = t >> 6, lane = t & 63;
    int l16 = lane & 15, l4 = lane >> 4;
    int wm = (wave >> 1) * 64, wn = (wave & 1) * 64;
    floatx4 acc[4][4] = {};
    int ktiles = K / BKK;
    for (int kt = 0; kt < ktiles; ++kt) {
        __syncthreads();
        // stage A: 128x32 bf16
#pragma unroll
        for (int p = 0; p < 2; ++p) {
            int c = t + p * 256;
            int r = c >> 2, kc = (c & 3) * 8;
            uint4 v = *(const uint4*)(A + (size_t)(bm + r) * K + kt * BKK + kc);
            *(uint4*)(&As[r][kc]) = v;
        }
        // stage B with transpose + fp32->bf16 convert: 32x128
#pragma unroll
        for (int p = 0; p < 2; ++p) {
            int c = t + p * 256;
            int kr = c >> 4, nc = (c & 15) * 8;
            const float* bp = B + (size_t)(kt * BKK + kr) * N + bn + nc;
            float e[8];
            load8(bp, e);
#pragma unroll
            for (int j = 0; j < 8; ++j) Bs[nc + j][kr] = f2b(e[j]);
        }
        __syncthreads();
        short8 af[4], bfr[4];
#pragma unroll
        for (int i = 0; i < 4; ++i)
            af[i] = *(const short8*)(&As[wm + i * 16 + l16][l4 * 8]);
#pragma unroll
        for (int i = 0; i < 4; ++i)
            bfr[i] = *(const short8*)(&Bs[wn + i * 16 + l16][l4 * 8]);
#pragma unroll
        for (int mi = 0; mi < 4; ++mi)
#pragma unroll
            for (int ni = 0; ni < 4; ++ni)
                acc[mi][ni] = __builtin_amdgcn_mfma_f32_16x16x32_bf16(af[mi], bfr[ni], acc[mi][ni], 0, 0, 0);
    }
    // epilogue: D frag: col = lane&15, row = (lane>>4)*4 + r
#pragma unroll
    for (int mi = 0; mi < 4; ++mi)
#pragma unroll
        for (int ni = 0; ni < 4; ++ni)
#pragma unroll
            for (int r = 0; r < 4; ++r) {
                int row = bm + wm + mi * 16 + l4 * 4 + r;
                int col = bn + wn + ni * 16 + l16;
                size_t idx = (size_t)row * N + col;
                float v = acc[mi][ni][r];
                if (MODE == 1) {
                    float a = AUXF ? ((const float*)AUXv)[idx] : b2f(((const ushort_t*)AUXv)[idx]);
                    v += a;
                }
                if (MODE == 2) {
                    float h = AUXF ? ((const float*)AUXv)[idx] : b2f(((const ushort_t*)AUXv)[idx]);
                    v = (h / (1.f + __expf(-h))) * v;
                }
                if (OUTF) ((float*)Cv)[idx] = v;
                else ((ushort_t*)Cv)[idx] = f2b(v);
            }
}

// ---------------- Flash attention (causal, GQA), all-bf16 operands ----------------
// grid: (T/64, N_HEADS, B). block 256 = 4 waves; wave owns 16 q rows. SBLK=32.
#define QB 64
#define SB 32

__global__ __launch_bounds__(256, 2) void attn_kernel(const ushort_t* __restrict__ Q,
                                                      const ushort_t* __restrict__ Kb,
                                                      const ushort_t* __restrict__ Vb,
                                                      ushort_t* __restrict__ O, int Tlen) {
    const int D = 2048, KVD = 512, dh = 128;
    int qt = blockIdx.x, h = blockIdx.y, b = blockIdx.z;
    int kv = h >> 2;  // G = 4
    int t = threadIdx.x, wave = t >> 6, lane = t & 63;
    int l16 = lane & 15, l4 = lane >> 4;
    __shared__ __align__(16) ushort_t Ks[SB][dh + 8];
    __shared__ __align__(16) ushort_t Vs[SB][dh + 8];
    __shared__ __align__(16) ushort_t Ps[4][16][40];
    int qbase = qt * QB;
    int qfrag = qbase + wave * 16;  // this wave's 16 rows
    short8 qf[4];
    const ushort_t* Qrow = Q + ((size_t)(b * Tlen) + qfrag + l16) * D + h * dh;
#pragma unroll
    for (int kk = 0; kk < 4; ++kk) qf[kk] = *(const short8*)(Qrow + kk * 32 + l4 * 8);
    floatx4 o_acc[8] = {};
    float m_r[4], l_r[4];
#pragma unroll
    for (int r = 0; r < 4; ++r) { m_r[r] = -INFINITY; l_r[r] = 0.f; }
    const float scale = 0.08838834764831845f;  // 128^-0.5
    int nst = (qbase + QB) / SB;
    for (int st = 0; st < nst; ++st) {
        __syncthreads();
#pragma unroll
        for (int p = 0; p < 2; ++p) {
            int c = t + p * 256;
            int s = c >> 4, kc = (c & 15) * 8;
            size_t goff = ((size_t)(b * Tlen) + st * SB + s) * KVD + kv * dh + kc;
            *(uint4*)(&Ks[s][kc]) = *(const uint4*)(Kb + goff);
            *(uint4*)(&Vs[s][kc]) = *(const uint4*)(Vb + goff);
        }
        __syncthreads();
        floatx4 s_acc[2] = {};
#pragma unroll
        for (int ss = 0; ss < 2; ++ss)
#pragma unroll
            for (int kk = 0; kk < 4; ++kk) {
                short8 kf = *(const short8*)(&Ks[ss * 16 + l16][kk * 32 + l4 * 8]);
                s_acc[ss] = __builtin_amdgcn_mfma_f32_16x16x32_bf16(qf[kk], kf, s_acc[ss], 0, 0, 0);
            }
        int s0 = st * SB;
        float sv[2][4], pmax[4];
#pragma unroll
        for (int r = 0; r < 4; ++r) pmax[r] = -INFINITY;
#pragma unroll
        for (int ss = 0; ss < 2; ++ss) {
            int scol = s0 + ss * 16 + l16;
#pragma unroll
            for (int r = 0; r < 4; ++r) {
                int qrow = qfrag + l4 * 4 + r;
                float v = s_acc[ss][r] * scale;
                if (scol > qrow) v = -INFINITY;
                sv[ss][r] = v;
                pmax[r] = fmaxf(pmax[r], v);
            }
        }
#pragma unroll
        for (int m = 1; m < 16; m <<= 1)
#pragma unroll
            for (int r = 0; r < 4; ++r) pmax[r] = fmaxf(pmax[r], __shfl_xor(pmax[r], m));
        float esc[4], rsum[4];
#pragma unroll
        for (int r = 0; r < 4; ++r) {
            float mn = fmaxf(m_r[r], pmax[r]);
            esc[r] = __expf(m_r[r] - mn);
            float rs = 0.f;
#pragma unroll
            for (int ss = 0; ss < 2; ++ss) {
                float p = __expf(sv[ss][r] - mn);
                sv[ss][r] = p;
                rs += p;
            }
            rsum[r] = rs;
            m_r[r] = mn;
        }
#pragma unroll
        for (int m = 1; m < 16; m <<= 1)
#pragma unroll
            for (int r = 0; r < 4; ++r) rsum[r] += __shfl_xor(rsum[r], m);
#pragma unroll
        for (int r = 0; r < 4; ++r) l_r[r] = l_r[r] * esc[r] + rsum[r];
#pragma unroll
        for (int c = 0; c < 8; ++c)
#pragma unroll
            for (int r = 0; r < 4; ++r) o_acc[c][r] *= esc[r];
#pragma unroll
        for (int ss = 0; ss < 2; ++ss)
#pragma unroll
            for (int r = 0; r < 4; ++r)
                Ps[wave][l4 * 4 + r][ss * 16 + l16] = f2b(sv[ss][r]);
        short8 pa = *(const short8*)(&Ps[wave][l16][l4 * 8]);
#pragma unroll
        for (int c = 0; c < 8; ++c) {
            short8 vf;
            ushort_t* vp = (ushort_t*)&vf;
#pragma unroll
            for (int j = 0; j < 8; ++j) vp[j] = Vs[l4 * 8 + j][c * 16 + l16];
            o_acc[c] = __builtin_amdgcn_mfma_f32_16x16x32_bf16(pa, vf, o_acc[c], 0, 0, 0);
        }
    }
#pragma unroll
    for (int c = 0; c < 8; ++c)
#pragma unroll
        for (int r = 0; r < 4; ++r) {
            int qrow = qfrag + l4 * 4 + r;
            int col = h * dh + c * 16 + l16;
            O[((size_t)(b * Tlen) + qrow) * D + col] = f2b(o_acc[c][r] / l_r[r]);
        }
}

extern "C" void kernel_launch(void* const* d_in, const int* in_sizes, int n_in,
                              void* d_out, int out_size, void* d_ws, size_t ws_size,
                              hipStream_t stream) {
    const float* x   = (const float*)d_in[0];
    const float* n1w = (const float*)d_in[1];
    const float* n2w = (const float*)d_in[2];
    const float* Wq  = (const float*)d_in[3];
    const float* Wk  = (const float*)d_in[4];
    const float* Wv  = (const float*)d_in[5];
    const float* Wo  = (const float*)d_in[6];
    const float* Wc  = (const float*)d_in[7];
    const float* W1  = (const float*)d_in[8];
    const float* W2  = (const float*)d_in[9];
    const float* W3  = (const float*)d_in[10];
    float* out = (float*)d_out;

    const int B = 2, T = 2048, D = 2048, F = 8192, KVD = 512;
    const int M = B * T;  // 4096
    const size_t XD   = (size_t)M * D * 2;     // 16.78 MB (bf16)
    const size_t XDF  = (size_t)M * D * 4;     // 33.55 MB (fp32)
    const size_t KVSZ = (size_t)M * KVD * 2;   // 4.19 MB

    char* w = (char*)d_ws;
    ushort_t* xn   = (ushort_t*)(w);                         // bf16 [M,D], also xn2
    ushort_t* qtmp = (ushort_t*)(w + XD);                    // bf16 [M,D], also att
    ushort_t* qfin = (ushort_t*)(w + 2 * XD);                // bf16 [M,D]
    float*    x2f  = (float*)   (w + 3 * XD);                // fp32 [M,D] residual stream
    ushort_t* kbuf = (ushort_t*)(w + 3 * XD + XDF);
    ushort_t* vbuf = (ushort_t*)(w + 3 * XD + XDF + KVSZ);
    ushort_t* h1   = (ushort_t*)(w + 3 * XD + XDF + 2 * KVSZ);  // bf16 [M,F] 67 MB

    dim3 blk(256);

    // xn = rmsnorm(x, n1)
    rmsnorm_kernel<<<M, blk, 0, stream>>>(x, n1w, xn, D);
    // qtmp = xn @ Wq
    gemm_kernel<0, false, false><<<dim3(M / BM, D / BN), blk, 0, stream>>>(xn, Wq, nullptr, qtmp, M, D, D);
    // qfin = qtmp @ Wc + qtmp   (q + pos)
    gemm_kernel<1, false, false><<<dim3(M / BM, D / BN), blk, 0, stream>>>(qtmp, Wc, qtmp, qfin, M, D, D);
    // k, v
    gemm_kernel<0, false, false><<<dim3(M / BM, KVD / BN), blk, 0, stream>>>(xn, Wk, nullptr, kbuf, M, KVD, D);
    gemm_kernel<0, false, false><<<dim3(M / BM, KVD / BN), blk, 0, stream>>>(xn, Wv, nullptr, vbuf, M, KVD, D);
    // attention -> att (reuse qtmp)
    attn_kernel<<<dim3(T / QB, 16, B), blk, 0, stream>>>(qfin, kbuf, vbuf, qtmp, T);
    // x2 = att @ Wo + x   (fp32 residual stream)
    gemm_kernel<1, true, true><<<dim3(M / BM, D / BN), blk, 0, stream>>>(qtmp, Wo, x, x2f, M, D, D);
    // xn2 = rmsnorm(x2, n2)  (into xn slot)
    rmsnorm_kernel<<<M, blk, 0, stream>>>(x2f, n2w, xn, D);
    // h1 = xn2 @ W1
    gemm_kernel<0, false, false><<<dim3(M / BM, F / BN), blk, 0, stream>>>(xn, W1, nullptr, h1, M, F, D);
    // h = silu(h1) * (xn2 @ W3)   in-place over h1
    gemm_kernel<2, false, false><<<dim3(M / BM, F / BN), blk, 0, stream>>>(xn, W3, h1, h1, M, F, D);
    // out = h @ W2 + x2   (fp32 out)
    gemm_kernel<1, true, true><<<dim3(M / BM, D / BN), blk, 0, stream>>>(h1, W2, x2f, out, M, D, F);
}

// Round 3
// 1191.440 us; speedup vs baseline: 2.3601x; 2.3601x over previous
//
#include <hip/hip_runtime.h>
#include <hip/hip_bf16.h>

typedef __attribute__((ext_vector_type(8))) short short8;
typedef __attribute__((ext_vector_type(4))) float floatx4;
typedef unsigned short ushort_t;

__device__ inline float b2f(ushort_t s) {
    return __uint_as_float(((unsigned int)s) << 16);
}
__device__ inline ushort_t f2b(float f) {
    unsigned int u = __float_as_uint(f);
    unsigned int r = 0x7fff + ((u >> 16) & 1);
    return (ushort_t)((u + r) >> 16);
}
__device__ inline void load8(const float* p, float* f) {
    float4 a = *(const float4*)p;
    float4 b = *(const float4*)(p + 4);
    f[0] = a.x; f[1] = a.y; f[2] = a.z; f[3] = a.w;
    f[4] = b.x; f[5] = b.y; f[6] = b.z; f[7] = b.w;
}
// async global->LDS, 16B per lane; lds base must be wave-uniform, global per-lane
__device__ inline void gload16(const ushort_t* g, ushort_t* l) {
    __builtin_amdgcn_global_load_lds(
        (const __attribute__((address_space(1))) unsigned int*)g,
        (__attribute__((address_space(3))) unsigned int*)l, 16, 0, 0);
}

// ---------- weight pre-pass: fp32 [K,N] -> bf16 [N,K] ----------
__global__ __launch_bounds__(256) void transpose_w(const float* __restrict__ src,
                                                   ushort_t* __restrict__ dst,
                                                   int K, int N) {
    __shared__ ushort_t tile[64][65];
    int kb = blockIdx.x * 64, nb = blockIdx.y * 64;
    int t = threadIdx.x;
#pragma unroll
    for (int i = 0; i < 4; ++i) {
        int r = (t >> 4) + i * 16;       // k offset 0..63
        int c = (t & 15) * 4;            // n offset
        float4 v = *(const float4*)(src + (size_t)(kb + r) * N + nb + c);
        tile[c + 0][r] = f2b(v.x);
        tile[c + 1][r] = f2b(v.y);
        tile[c + 2][r] = f2b(v.z);
        tile[c + 3][r] = f2b(v.w);
    }
    __syncthreads();
#pragma unroll
    for (int i = 0; i < 2; ++i) {
        int s = t + i * 256;
        int n = s >> 3, kc = (s & 7) * 8;
        ushort_t o[8];
#pragma unroll
        for (int j = 0; j < 8; ++j) o[j] = tile[n][kc + j];
        *(uint4*)(dst + (size_t)(nb + n) * K + kb + kc) = *(const uint4*)o;
    }
}

// ---------------- RMSNorm: fp32 in -> bf16 out. one block per row, D=2048 ----------------
__global__ __launch_bounds__(256) void rmsnorm_kernel(const float* __restrict__ x,
                                                      const float* __restrict__ w,
                                                      ushort_t* __restrict__ out, int D) {
    int row = blockIdx.x;
    int t = threadIdx.x;
    const float* xr = x + (size_t)row * D;
    float f[8];
    load8(xr + t * 8, f);
    float ss = 0.f;
#pragma unroll
    for (int i = 0; i < 8; ++i) ss += f[i] * f[i];
#pragma unroll
    for (int m = 1; m < 64; m <<= 1) ss += __shfl_xor(ss, m);
    __shared__ float wsum[4];
    if ((t & 63) == 0) wsum[t >> 6] = ss;
    __syncthreads();
    float tot = wsum[0] + wsum[1] + wsum[2] + wsum[3];
    float r = rsqrtf(tot / (float)D + 1e-6f);
    float wf[8];
    load8(w + t * 8, wf);
    ushort_t o[8];
#pragma unroll
    for (int i = 0; i < 8; ++i) o[i] = f2b(f[i] * r * wf[i]);
    *(uint4*)(out + (size_t)row * D + t * 8) = *(const uint4*)o;
}

// ---------------- m97-structure GEMM: C[M,N] = A[M,K](bf16) * Bt[N,K](bf16) ----------------
// MODE 0: C = AB ; MODE 1: C = AB + AUX ; MODE 2: C = silu(AUX) * AB
#define BM 128
#define BN 128
#define BK 32

template <int MODE, bool AUXF, bool OUTF>
__global__ __launch_bounds__(256, 2) void gemm_bt(const ushort_t* __restrict__ A,
                                                  const ushort_t* __restrict__ Bt,
                                                  const void* __restrict__ AUXv,
                                                  void* __restrict__ Cv,
                                                  int M, int N, int K) {
    __shared__ __align__(16) ushort_t As[BM * BK];
    __shared__ __align__(16) ushort_t Bs[BN * BK];
    int t = threadIdx.x, wave = t >> 6, lane = t & 63;
    int l16 = lane & 15, l4 = lane >> 4;
    int bm = blockIdx.x * BM, bn = blockIdx.y * BN;
    int wm = (wave >> 1) * 64, wn = (wave & 1) * 64;
    floatx4 acc[4][4] = {};
    // staging: wave covers rows [wave*32, wave*32+32) in two 16-row chunks
    const ushort_t* gA = A + (size_t)(bm + wave * 32 + (lane >> 2)) * K + (lane & 3) * 8;
    const ushort_t* gB = Bt + (size_t)(bn + wave * 32 + (lane >> 2)) * K + (lane & 3) * 8;
    ushort_t* lA = As + wave * 32 * BK;
    ushort_t* lB = Bs + wave * 32 * BK;
    int ktiles = K / BK;
    for (int kt = 0; kt < ktiles; ++kt) {
        __syncthreads();
        int k0 = kt * BK;
        gload16(gA + k0, lA);
        gload16(gA + 16 * K + k0, lA + 16 * BK);
        gload16(gB + k0, lB);
        gload16(gB + 16 * K + k0, lB + 16 * BK);
        __syncthreads();  // drains vmcnt before barrier
        short8 af[4], bf[4];
#pragma unroll
        for (int i = 0; i < 4; ++i)
            af[i] = *(const short8*)(As + (wm + i * 16 + l16) * BK + l4 * 8);
#pragma unroll
        for (int i = 0; i < 4; ++i)
            bf[i] = *(const short8*)(Bs + (wn + i * 16 + l16) * BK + l4 * 8);
#pragma unroll
        for (int mi = 0; mi < 4; ++mi)
#pragma unroll
            for (int ni = 0; ni < 4; ++ni)
                acc[mi][ni] = __builtin_amdgcn_mfma_f32_16x16x32_bf16(af[mi], bf[ni], acc[mi][ni], 0, 0, 0);
    }
    // epilogue: D frag: col = lane&15, row = (lane>>4)*4 + r
#pragma unroll
    for (int mi = 0; mi < 4; ++mi)
#pragma unroll
        for (int ni = 0; ni < 4; ++ni)
#pragma unroll
            for (int r = 0; r < 4; ++r) {
                int row = bm + wm + mi * 16 + l4 * 4 + r;
                int col = bn + wn + ni * 16 + l16;
                size_t idx = (size_t)row * N + col;
                float v = acc[mi][ni][r];
                if (MODE == 1) {
                    float a = AUXF ? ((const float*)AUXv)[idx] : b2f(((const ushort_t*)AUXv)[idx]);
                    v += a;
                }
                if (MODE == 2) {
                    float h = AUXF ? ((const float*)AUXv)[idx] : b2f(((const ushort_t*)AUXv)[idx]);
                    v = (h / (1.f + __expf(-h))) * v;
                }
                if (OUTF) ((float*)Cv)[idx] = v;
                else ((ushort_t*)Cv)[idx] = f2b(v);
            }
}

// ---------------- Flash attention (causal, GQA), all-bf16 operands ----------------
#define QB 64
#define SB 32

__global__ __launch_bounds__(256, 2) void attn_kernel(const ushort_t* __restrict__ Q,
                                                      const ushort_t* __restrict__ Kb,
                                                      const ushort_t* __restrict__ Vb,
                                                      ushort_t* __restrict__ O, int Tlen) {
    const int D = 2048, KVD = 512, dh = 128;
    int qt = blockIdx.x, h = blockIdx.y, b = blockIdx.z;
    int kv = h >> 2;  // G = 4
    int t = threadIdx.x, wave = t >> 6, lane = t & 63;
    int l16 = lane & 15, l4 = lane >> 4;
    __shared__ __align__(16) ushort_t Ks[SB][dh + 8];
    __shared__ __align__(16) ushort_t Vs[SB][dh + 8];
    __shared__ __align__(16) ushort_t Ps[4][16][40];
    int qbase = qt * QB;
    int qfrag = qbase + wave * 16;
    short8 qf[4];
    const ushort_t* Qrow = Q + ((size_t)(b * Tlen) + qfrag + l16) * D + h * dh;
#pragma unroll
    for (int kk = 0; kk < 4; ++kk) qf[kk] = *(const short8*)(Qrow + kk * 32 + l4 * 8);
    floatx4 o_acc[8] = {};
    float m_r[4], l_r[4];
#pragma unroll
    for (int r = 0; r < 4; ++r) { m_r[r] = -INFINITY; l_r[r] = 0.f; }
    const float scale = 0.08838834764831845f;
    int nst = (qbase + QB) / SB;
    for (int st = 0; st < nst; ++st) {
        __syncthreads();
#pragma unroll
        for (int p = 0; p < 2; ++p) {
            int c = t + p * 256;
            int s = c >> 4, kc = (c & 15) * 8;
            size_t goff = ((size_t)(b * Tlen) + st * SB + s) * KVD + kv * dh + kc;
            *(uint4*)(&Ks[s][kc]) = *(const uint4*)(Kb + goff);
            *(uint4*)(&Vs[s][kc]) = *(const uint4*)(Vb + goff);
        }
        __syncthreads();
        floatx4 s_acc[2] = {};
#pragma unroll
        for (int ss = 0; ss < 2; ++ss)
#pragma unroll
            for (int kk = 0; kk < 4; ++kk) {
                short8 kf = *(const short8*)(&Ks[ss * 16 + l16][kk * 32 + l4 * 8]);
                s_acc[ss] = __builtin_amdgcn_mfma_f32_16x16x32_bf16(qf[kk], kf, s_acc[ss], 0, 0, 0);
            }
        int s0 = st * SB;
        float sv[2][4], pmax[4];
#pragma unroll
        for (int r = 0; r < 4; ++r) pmax[r] = -INFINITY;
#pragma unroll
        for (int ss = 0; ss < 2; ++ss) {
            int scol = s0 + ss * 16 + l16;
#pragma unroll
            for (int r = 0; r < 4; ++r) {
                int qrow = qfrag + l4 * 4 + r;
                float v = s_acc[ss][r] * scale;
                if (scol > qrow) v = -INFINITY;
                sv[ss][r] = v;
                pmax[r] = fmaxf(pmax[r], v);
            }
        }
#pragma unroll
        for (int m = 1; m < 16; m <<= 1)
#pragma unroll
            for (int r = 0; r < 4; ++r) pmax[r] = fmaxf(pmax[r], __shfl_xor(pmax[r], m));
        float esc[4], rsum[4];
#pragma unroll
        for (int r = 0; r < 4; ++r) {
            float mn = fmaxf(m_r[r], pmax[r]);
            esc[r] = __expf(m_r[r] - mn);
            float rs = 0.f;
#pragma unroll
            for (int ss = 0; ss < 2; ++ss) {
                float p = __expf(sv[ss][r] - mn);
                sv[ss][r] = p;
                rs += p;
            }
            rsum[r] = rs;
            m_r[r] = mn;
        }
#pragma unroll
        for (int m = 1; m < 16; m <<= 1)
#pragma unroll
            for (int r = 0; r < 4; ++r) rsum[r] += __shfl_xor(rsum[r], m);
#pragma unroll
        for (int r = 0; r < 4; ++r) l_r[r] = l_r[r] * esc[r] + rsum[r];
#pragma unroll
        for (int c = 0; c < 8; ++c)
#pragma unroll
            for (int r = 0; r < 4; ++r) o_acc[c][r] *= esc[r];
#pragma unroll
        for (int ss = 0; ss < 2; ++ss)
#pragma unroll
            for (int r = 0; r < 4; ++r)
                Ps[wave][l4 * 4 + r][ss * 16 + l16] = f2b(sv[ss][r]);
        short8 pa = *(const short8*)(&Ps[wave][l16][l4 * 8]);
#pragma unroll
        for (int c = 0; c < 8; ++c) {
            short8 vf;
            ushort_t* vp = (ushort_t*)&vf;
#pragma unroll
            for (int j = 0; j < 8; ++j) vp[j] = Vs[l4 * 8 + j][c * 16 + l16];
            o_acc[c] = __builtin_amdgcn_mfma_f32_16x16x32_bf16(pa, vf, o_acc[c], 0, 0, 0);
        }
    }
#pragma unroll
    for (int c = 0; c < 8; ++c)
#pragma unroll
        for (int r = 0; r < 4; ++r) {
            int qrow = qfrag + l4 * 4 + r;
            int col = h * dh + c * 16 + l16;
            O[((size_t)(b * Tlen) + qrow) * D + col] = f2b(o_acc[c][r] / l_r[r]);
        }
}

extern "C" void kernel_launch(void* const* d_in, const int* in_sizes, int n_in,
                              void* d_out, int out_size, void* d_ws, size_t ws_size,
                              hipStream_t stream) {
    const float* x   = (const float*)d_in[0];
    const float* n1w = (const float*)d_in[1];
    const float* n2w = (const float*)d_in[2];
    const float* Wq  = (const float*)d_in[3];
    const float* Wk  = (const float*)d_in[4];
    const float* Wv  = (const float*)d_in[5];
    const float* Wo  = (const float*)d_in[6];
    const float* Wc  = (const float*)d_in[7];
    const float* W1  = (const float*)d_in[8];
    const float* W2  = (const float*)d_in[9];
    const float* W3  = (const float*)d_in[10];
    float* out = (float*)d_out;

    const int B = 2, T = 2048, D = 2048, F = 8192, KVD = 512;
    const int M = B * T;  // 4096
    const size_t XD   = (size_t)M * D * 2;     // 16.78 MB
    const size_t XDF  = (size_t)M * D * 4;     // 33.55 MB
    const size_t KVSZ = (size_t)M * KVD * 2;   // 4.19 MB
    const size_t MF   = (size_t)M * F * 2;     // 67.1 MB
    const size_t WDD  = (size_t)D * D * 2;     // 8.39 MB
    const size_t WDK  = (size_t)D * KVD * 2;   // 2.10 MB
    const size_t WDF  = (size_t)D * F * 2;     // 33.55 MB

    char* w = (char*)d_ws;
    ushort_t* xn   = (ushort_t*)(w);
    ushort_t* qtmp = (ushort_t*)(w + XD);
    ushort_t* qfin = (ushort_t*)(w + 2 * XD);
    float*    x2f  = (float*)   (w + 3 * XD);
    ushort_t* kbuf = (ushort_t*)(w + 3 * XD + XDF);
    ushort_t* vbuf = (ushort_t*)(w + 3 * XD + XDF + KVSZ);
    ushort_t* h1   = (ushort_t*)(w + 3 * XD + XDF + 2 * KVSZ);
    char* wt = w + 3 * XD + XDF + 2 * KVSZ + MF;
    ushort_t* WqT = (ushort_t*)(wt);
    ushort_t* WcT = (ushort_t*)(wt + WDD);
    ushort_t* WoT = (ushort_t*)(wt + 2 * WDD);
    ushort_t* WkT = (ushort_t*)(wt + 3 * WDD);
    ushort_t* WvT = (ushort_t*)(wt + 3 * WDD + WDK);
    ushort_t* W1T = (ushort_t*)(wt + 3 * WDD + 2 * WDK);
    ushort_t* W3T = (ushort_t*)(wt + 3 * WDD + 2 * WDK + WDF);
    ushort_t* W2T = (ushort_t*)(wt + 3 * WDD + 2 * WDK + 2 * WDF);

    dim3 blk(256);

    // weight pre-pass: fp32 [K,N] -> bf16 [N,K]
    transpose_w<<<dim3(D / 64, D / 64), blk, 0, stream>>>(Wq, WqT, D, D);
    transpose_w<<<dim3(D / 64, D / 64), blk, 0, stream>>>(Wc, WcT, D, D);
    transpose_w<<<dim3(D / 64, D / 64), blk, 0, stream>>>(Wo, WoT, D, D);
    transpose_w<<<dim3(D / 64, KVD / 64), blk, 0, stream>>>(Wk, WkT, D, KVD);
    transpose_w<<<dim3(D / 64, KVD / 64), blk, 0, stream>>>(Wv, WvT, D, KVD);
    transpose_w<<<dim3(D / 64, F / 64), blk, 0, stream>>>(W1, W1T, D, F);
    transpose_w<<<dim3(D / 64, F / 64), blk, 0, stream>>>(W3, W3T, D, F);
    transpose_w<<<dim3(F / 64, D / 64), blk, 0, stream>>>(W2, W2T, F, D);

    // xn = rmsnorm(x, n1)
    rmsnorm_kernel<<<M, blk, 0, stream>>>(x, n1w, xn, D);
    // qtmp = xn @ Wq
    gemm_bt<0, false, false><<<dim3(M / BM, D / BN), blk, 0, stream>>>(xn, WqT, nullptr, qtmp, M, D, D);
    // qfin = qtmp @ Wc + qtmp   (q + pos)
    gemm_bt<1, false, false><<<dim3(M / BM, D / BN), blk, 0, stream>>>(qtmp, WcT, qtmp, qfin, M, D, D);
    // k, v
    gemm_bt<0, false, false><<<dim3(M / BM, KVD / BN), blk, 0, stream>>>(xn, WkT, nullptr, kbuf, M, KVD, D);
    gemm_bt<0, false, false><<<dim3(M / BM, KVD / BN), blk, 0, stream>>>(xn, WvT, nullptr, vbuf, M, KVD, D);
    // attention -> att (reuse qtmp)
    attn_kernel<<<dim3(T / QB, 16, B), blk, 0, stream>>>(qfin, kbuf, vbuf, qtmp, T);
    // x2 = att @ Wo + x   (fp32 residual stream)
    gemm_bt<1, true, true><<<dim3(M / BM, D / BN), blk, 0, stream>>>(qtmp, WoT, x, x2f, M, D, D);
    // xn2 = rmsnorm(x2, n2)
    rmsnorm_kernel<<<M, blk, 0, stream>>>(x2f, n2w, xn, D);
    // h1 = xn2 @ W1
    gemm_bt<0, false, false><<<dim3(M / BM, F / BN), blk, 0, stream>>>(xn, W1T, nullptr, h1, M, F, D);
    // h = silu(h1) * (xn2 @ W3)   in-place over h1
    gemm_bt<2, false, false><<<dim3(M / BM, F / BN), blk, 0, stream>>>(xn, W3T, h1, h1, M, F, D);
    // out = h @ W2 + x2   (fp32 out)
    gemm_bt<1, true, true><<<dim3(M / BM, D / BN), blk, 0, stream>>>(h1, W2T, x2f, out, M, D, F);
}

// Round 4
// 1129.472 us; speedup vs baseline: 2.4896x; 1.0549x over previous
//
#include <hip/hip_runtime.h>
#include <hip/hip_bf16.h>

typedef __attribute__((ext_vector_type(8))) short short8;
typedef __attribute__((ext_vector_type(4))) float floatx4;
typedef unsigned short ushort_t;

__device__ inline float b2f(ushort_t s) {
    return __uint_as_float(((unsigned int)s) << 16);
}
__device__ inline ushort_t f2b(float f) {
    unsigned int u = __float_as_uint(f);
    unsigned int r = 0x7fff + ((u >> 16) & 1);
    return (ushort_t)((u + r) >> 16);
}
__device__ inline void load8(const float* p, float* f) {
    float4 a = *(const float4*)p;
    float4 b = *(const float4*)(p + 4);
    f[0] = a.x; f[1] = a.y; f[2] = a.z; f[3] = a.w;
    f[4] = b.x; f[5] = b.y; f[6] = b.z; f[7] = b.w;
}
// async global->LDS, 16B per lane; lds base must be wave-uniform, global per-lane
__device__ inline void gload16(const ushort_t* g, ushort_t* l) {
    __builtin_amdgcn_global_load_lds(
        (const __attribute__((address_space(1))) unsigned int*)g,
        (__attribute__((address_space(3))) unsigned int*)l, 16, 0, 0);
}

// ---------- weight pre-pass: fp32 [K,N] -> bf16 [N,K] ----------
__global__ __launch_bounds__(256) void transpose_w(const float* __restrict__ src,
                                                   ushort_t* __restrict__ dst,
                                                   int K, int N) {
    __shared__ ushort_t tile[64][65];
    int kb = blockIdx.x * 64, nb = blockIdx.y * 64;
    int t = threadIdx.x;
#pragma unroll
    for (int i = 0; i < 4; ++i) {
        int r = (t >> 4) + i * 16;
        int c = (t & 15) * 4;
        float4 v = *(const float4*)(src + (size_t)(kb + r) * N + nb + c);
        tile[c + 0][r] = f2b(v.x);
        tile[c + 1][r] = f2b(v.y);
        tile[c + 2][r] = f2b(v.z);
        tile[c + 3][r] = f2b(v.w);
    }
    __syncthreads();
#pragma unroll
    for (int i = 0; i < 2; ++i) {
        int s = t + i * 256;
        int n = s >> 3, kc = (s & 7) * 8;
        ushort_t o[8];
#pragma unroll
        for (int j = 0; j < 8; ++j) o[j] = tile[n][kc + j];
        *(uint4*)(dst + (size_t)(nb + n) * K + kb + kc) = *(const uint4*)o;
    }
}

// ---------------- RMSNorm: fp32 in -> bf16 out ----------------
__global__ __launch_bounds__(256) void rmsnorm_kernel(const float* __restrict__ x,
                                                      const float* __restrict__ w,
                                                      ushort_t* __restrict__ out, int D) {
    int row = blockIdx.x;
    int t = threadIdx.x;
    const float* xr = x + (size_t)row * D;
    float f[8];
    load8(xr + t * 8, f);
    float ss = 0.f;
#pragma unroll
    for (int i = 0; i < 8; ++i) ss += f[i] * f[i];
#pragma unroll
    for (int m = 1; m < 64; m <<= 1) ss += __shfl_xor(ss, m);
    __shared__ float wsum[4];
    if ((t & 63) == 0) wsum[t >> 6] = ss;
    __syncthreads();
    float tot = wsum[0] + wsum[1] + wsum[2] + wsum[3];
    float r = rsqrtf(tot / (float)D + 1e-6f);
    float wf[8];
    load8(w + t * 8, wf);
    ushort_t o[8];
#pragma unroll
    for (int i = 0; i < 8; ++i) o[i] = f2b(f[i] * r * wf[i]);
    *(uint4*)(out + (size_t)row * D + t * 8) = *(const uint4*)o;
}

// ---------------- m97-structure GEMM: C[M,N] = A[M,K](bf16) * Bt[N,K](bf16) ----------------
// MODE 0: C = AB ; MODE 1: C = AB + AUX ; MODE 2: C = silu(AUX) * AB
// OUTT: store transposed C^T[n][m] (bf16) for attention V
#define BM 128
#define BN 128
#define BK 32

template <int MODE, bool AUXF, bool OUTF, bool OUTT = false>
__global__ __launch_bounds__(256, 2) void gemm_bt(const ushort_t* __restrict__ A,
                                                  const ushort_t* __restrict__ Bt,
                                                  const void* __restrict__ AUXv,
                                                  void* __restrict__ Cv,
                                                  int M, int N, int K) {
    __shared__ __align__(16) ushort_t As[BM * BK];
    __shared__ __align__(16) ushort_t Bs[BN * BK];
    int t = threadIdx.x, wave = t >> 6, lane = t & 63;
    int l16 = lane & 15, l4 = lane >> 4;
    int bm = blockIdx.x * BM, bn = blockIdx.y * BN;
    int wm = (wave >> 1) * 64, wn = (wave & 1) * 64;
    floatx4 acc[4][4] = {};
    const ushort_t* gA = A + (size_t)(bm + wave * 32 + (lane >> 2)) * K + (lane & 3) * 8;
    const ushort_t* gB = Bt + (size_t)(bn + wave * 32 + (lane >> 2)) * K + (lane & 3) * 8;
    ushort_t* lA = As + wave * 32 * BK;
    ushort_t* lB = Bs + wave * 32 * BK;
    int ktiles = K / BK;
    for (int kt = 0; kt < ktiles; ++kt) {
        __syncthreads();
        int k0 = kt * BK;
        gload16(gA + k0, lA);
        gload16(gA + 16 * K + k0, lA + 16 * BK);
        gload16(gB + k0, lB);
        gload16(gB + 16 * K + k0, lB + 16 * BK);
        __syncthreads();
        short8 af[4], bf[4];
#pragma unroll
        for (int i = 0; i < 4; ++i)
            af[i] = *(const short8*)(As + (wm + i * 16 + l16) * BK + l4 * 8);
#pragma unroll
        for (int i = 0; i < 4; ++i)
            bf[i] = *(const short8*)(Bs + (wn + i * 16 + l16) * BK + l4 * 8);
#pragma unroll
        for (int mi = 0; mi < 4; ++mi)
#pragma unroll
            for (int ni = 0; ni < 4; ++ni)
                acc[mi][ni] = __builtin_amdgcn_mfma_f32_16x16x32_bf16(af[mi], bf[ni], acc[mi][ni], 0, 0, 0);
    }
#pragma unroll
    for (int mi = 0; mi < 4; ++mi)
#pragma unroll
        for (int ni = 0; ni < 4; ++ni)
#pragma unroll
            for (int r = 0; r < 4; ++r) {
                int row = bm + wm + mi * 16 + l4 * 4 + r;
                int col = bn + wn + ni * 16 + l16;
                size_t idx = (size_t)row * N + col;
                float v = acc[mi][ni][r];
                if (MODE == 1) {
                    float a = AUXF ? ((const float*)AUXv)[idx] : b2f(((const ushort_t*)AUXv)[idx]);
                    v += a;
                }
                if (MODE == 2) {
                    float h = AUXF ? ((const float*)AUXv)[idx] : b2f(((const ushort_t*)AUXv)[idx]);
                    v = (h / (1.f + __expf(-h))) * v;
                }
                if (OUTT) ((ushort_t*)Cv)[(size_t)col * M + row] = f2b(v);
                else if (OUTF) ((float*)Cv)[idx] = v;
                else ((ushort_t*)Cv)[idx] = f2b(v);
            }
}

// ---------------- Flash attention (causal, GQA) ----------------
// grid: (T/128, N_HEADS, B). block 256 = 4 waves; wave owns 32 q rows (2 frags). SB=32.
// V comes pre-transposed: VbT[d_global][token]
#define QB 128
#define SB 32

__global__ __launch_bounds__(256, 2) void attn_kernel(const ushort_t* __restrict__ Q,
                                                      const ushort_t* __restrict__ Kb,
                                                      const ushort_t* __restrict__ VbT,
                                                      ushort_t* __restrict__ O, int Tlen) {
    const int D = 2048, KVD = 512, dh = 128;
    const int MTOK = 4096;  // B*T (vbufT row length)
    int qt = blockIdx.x, h = blockIdx.y, b = blockIdx.z;
    int kv = h >> 2;  // G = 4
    int t = threadIdx.x, wave = t >> 6, lane = t & 63;
    int l16 = lane & 15, l4 = lane >> 4;
    __shared__ __align__(16) ushort_t Ks[SB][dh + 8];    // [s][d]
    __shared__ __align__(16) ushort_t Vt[dh][SB + 8];    // [d][s]
    __shared__ __align__(16) ushort_t Ps[8][16][40];     // per (wave,frag)
    int qbase = qt * QB;
    int qfrag = qbase + wave * 32;
    short8 qf[2][4];
#pragma unroll
    for (int f = 0; f < 2; ++f) {
        const ushort_t* Qrow = Q + ((size_t)(b * Tlen) + qfrag + f * 16 + l16) * D + h * dh;
#pragma unroll
        for (int kk = 0; kk < 4; ++kk) qf[f][kk] = *(const short8*)(Qrow + kk * 32 + l4 * 8);
    }
    floatx4 o_acc[2][8] = {};
    float m_r[2][4], l_r[2][4];
#pragma unroll
    for (int f = 0; f < 2; ++f)
#pragma unroll
        for (int r = 0; r < 4; ++r) { m_r[f][r] = -INFINITY; l_r[f][r] = 0.f; }
    const float scale = 0.08838834764831845f;
    int nst = (qbase + QB) / SB;
    // staging regs (T14: issue early, write late)
    uint4 kreg[2], vreg[2];
    int ks_s = 0, ks_d = 0, vs_d = 0, vs_s = 0;
    {
        int c = t;
        ks_s = c >> 4; ks_d = (c & 15) * 8;
        vs_d = c >> 2; vs_s = (c & 3) * 8;
    }
    const ushort_t* Kg = Kb + ((size_t)(b * Tlen) + ks_s) * KVD + kv * dh + ks_d;
    const ushort_t* Kg2 = Kb + ((size_t)(b * Tlen) + ks_s + 16) * KVD + kv * dh + ks_d;
    const ushort_t* Vg = VbT + (size_t)(kv * dh + vs_d) * MTOK + b * Tlen + vs_s;
    const ushort_t* Vg2 = VbT + (size_t)(kv * dh + vs_d + 64) * MTOK + b * Tlen + vs_s;
    // prologue: load tile 0
    kreg[0] = *(const uint4*)(Kg);
    kreg[1] = *(const uint4*)(Kg2);
    vreg[0] = *(const uint4*)(Vg);
    vreg[1] = *(const uint4*)(Vg2);
    for (int st = 0; st < nst; ++st) {
        __syncthreads();
        // write staged regs to LDS
        *(uint4*)(&Ks[ks_s][ks_d]) = kreg[0];
        *(uint4*)(&Ks[ks_s + 16][ks_d]) = kreg[1];
        *(uint4*)(&Vt[vs_d][vs_s]) = vreg[0];
        *(uint4*)(&Vt[vs_d + 64][vs_s]) = vreg[1];
        __syncthreads();
        // prefetch next tile (latency hides under compute)
        if (st + 1 < nst) {
            int off = (st + 1) * SB;
            kreg[0] = *(const uint4*)(Kg + (size_t)off * KVD);
            kreg[1] = *(const uint4*)(Kg2 + (size_t)off * KVD);
            vreg[0] = *(const uint4*)(Vg + off);
            vreg[1] = *(const uint4*)(Vg2 + off);
        }
        int s0 = st * SB;
        if (s0 < qfrag + 32) {
            // QK^T for both row-frags, K frags shared
            floatx4 sa[2][2] = {};
#pragma unroll
            for (int ss = 0; ss < 2; ++ss)
#pragma unroll
                for (int kk = 0; kk < 4; ++kk) {
                    short8 kf = *(const short8*)(&Ks[ss * 16 + l16][kk * 32 + l4 * 8]);
                    sa[0][ss] = __builtin_amdgcn_mfma_f32_16x16x32_bf16(qf[0][kk], kf, sa[0][ss], 0, 0, 0);
                    sa[1][ss] = __builtin_amdgcn_mfma_f32_16x16x32_bf16(qf[1][kk], kf, sa[1][ss], 0, 0, 0);
                }
#pragma unroll
            for (int f = 0; f < 2; ++f) {
                float sv[2][4], pmax[4];
#pragma unroll
                for (int r = 0; r < 4; ++r) pmax[r] = -INFINITY;
#pragma unroll
                for (int ss = 0; ss < 2; ++ss) {
                    int scol = s0 + ss * 16 + l16;
#pragma unroll
                    for (int r = 0; r < 4; ++r) {
                        int qrow = qfrag + f * 16 + l4 * 4 + r;
                        float v = sa[f][ss][r] * scale;
                        if (scol > qrow) v = -INFINITY;
                        sv[ss][r] = v;
                        pmax[r] = fmaxf(pmax[r], v);
                    }
                }
#pragma unroll
                for (int m = 1; m < 16; m <<= 1)
#pragma unroll
                    for (int r = 0; r < 4; ++r) pmax[r] = fmaxf(pmax[r], __shfl_xor(pmax[r], m));
                float esc[4], rsum[4];
#pragma unroll
                for (int r = 0; r < 4; ++r) {
                    float mn = fmaxf(m_r[f][r], pmax[r]);
                    esc[r] = __expf(m_r[f][r] - mn);
                    float rs = 0.f;
#pragma unroll
                    for (int ss = 0; ss < 2; ++ss) {
                        float p = __expf(sv[ss][r] - mn);
                        sv[ss][r] = p;
                        rs += p;
                    }
                    rsum[r] = rs;
                    m_r[f][r] = mn;
                }
#pragma unroll
                for (int m = 1; m < 16; m <<= 1)
#pragma unroll
                    for (int r = 0; r < 4; ++r) rsum[r] += __shfl_xor(rsum[r], m);
#pragma unroll
                for (int r = 0; r < 4; ++r) l_r[f][r] = l_r[f][r] * esc[r] + rsum[r];
#pragma unroll
                for (int c = 0; c < 8; ++c)
#pragma unroll
                    for (int r = 0; r < 4; ++r) o_acc[f][c][r] *= esc[r];
#pragma unroll
                for (int ss = 0; ss < 2; ++ss)
#pragma unroll
                    for (int r = 0; r < 4; ++r)
                        Ps[wave * 2 + f][l4 * 4 + r][ss * 16 + l16] = f2b(sv[ss][r]);
            }
            short8 pa0 = *(const short8*)(&Ps[wave * 2 + 0][l16][l4 * 8]);
            short8 pa1 = *(const short8*)(&Ps[wave * 2 + 1][l16][l4 * 8]);
#pragma unroll
            for (int c = 0; c < 8; ++c) {
                short8 vf = *(const short8*)(&Vt[c * 16 + l16][l4 * 8]);
                o_acc[0][c] = __builtin_amdgcn_mfma_f32_16x16x32_bf16(pa0, vf, o_acc[0][c], 0, 0, 0);
                o_acc[1][c] = __builtin_amdgcn_mfma_f32_16x16x32_bf16(pa1, vf, o_acc[1][c], 0, 0, 0);
            }
        }
    }
#pragma unroll
    for (int f = 0; f < 2; ++f)
#pragma unroll
        for (int c = 0; c < 8; ++c)
#pragma unroll
            for (int r = 0; r < 4; ++r) {
                int qrow = qfrag + f * 16 + l4 * 4 + r;
                int col = h * dh + c * 16 + l16;
                O[((size_t)(b * Tlen) + qrow) * D + col] = f2b(o_acc[f][c][r] / l_r[f][r]);
            }
}

extern "C" void kernel_launch(void* const* d_in, const int* in_sizes, int n_in,
                              void* d_out, int out_size, void* d_ws, size_t ws_size,
                              hipStream_t stream) {
    const float* x   = (const float*)d_in[0];
    const float* n1w = (const float*)d_in[1];
    const float* n2w = (const float*)d_in[2];
    const float* Wq  = (const float*)d_in[3];
    const float* Wk  = (const float*)d_in[4];
    const float* Wv  = (const float*)d_in[5];
    const float* Wo  = (const float*)d_in[6];
    const float* Wc  = (const float*)d_in[7];
    const float* W1  = (const float*)d_in[8];
    const float* W2  = (const float*)d_in[9];
    const float* W3  = (const float*)d_in[10];
    float* out = (float*)d_out;

    const int B = 2, T = 2048, D = 2048, F = 8192, KVD = 512;
    const int M = B * T;  // 4096
    const size_t XD   = (size_t)M * D * 2;
    const size_t XDF  = (size_t)M * D * 4;
    const size_t KVSZ = (size_t)M * KVD * 2;
    const size_t MF   = (size_t)M * F * 2;
    const size_t WDD  = (size_t)D * D * 2;
    const size_t WDK  = (size_t)D * KVD * 2;
    const size_t WDF  = (size_t)D * F * 2;

    char* w = (char*)d_ws;
    ushort_t* xn    = (ushort_t*)(w);
    ushort_t* qtmp  = (ushort_t*)(w + XD);
    ushort_t* qfin  = (ushort_t*)(w + 2 * XD);
    float*    x2f   = (float*)   (w + 3 * XD);
    ushort_t* kbuf  = (ushort_t*)(w + 3 * XD + XDF);
    ushort_t* vbufT = (ushort_t*)(w + 3 * XD + XDF + KVSZ);  // [KVD][M] transposed
    ushort_t* h1    = (ushort_t*)(w + 3 * XD + XDF + 2 * KVSZ);
    char* wt = w + 3 * XD + XDF + 2 * KVSZ + MF;
    ushort_t* WqT = (ushort_t*)(wt);
    ushort_t* WcT = (ushort_t*)(wt + WDD);
    ushort_t* WoT = (ushort_t*)(wt + 2 * WDD);
    ushort_t* WkT = (ushort_t*)(wt + 3 * WDD);
    ushort_t* WvT = (ushort_t*)(wt + 3 * WDD + WDK);
    ushort_t* W1T = (ushort_t*)(wt + 3 * WDD + 2 * WDK);
    ushort_t* W3T = (ushort_t*)(wt + 3 * WDD + 2 * WDK + WDF);
    ushort_t* W2T = (ushort_t*)(wt + 3 * WDD + 2 * WDK + 2 * WDF);

    dim3 blk(256);

    transpose_w<<<dim3(D / 64, D / 64), blk, 0, stream>>>(Wq, WqT, D, D);
    transpose_w<<<dim3(D / 64, D / 64), blk, 0, stream>>>(Wc, WcT, D, D);
    transpose_w<<<dim3(D / 64, D / 64), blk, 0, stream>>>(Wo, WoT, D, D);
    transpose_w<<<dim3(D / 64, KVD / 64), blk, 0, stream>>>(Wk, WkT, D, KVD);
    transpose_w<<<dim3(D / 64, KVD / 64), blk, 0, stream>>>(Wv, WvT, D, KVD);
    transpose_w<<<dim3(D / 64, F / 64), blk, 0, stream>>>(W1, W1T, D, F);
    transpose_w<<<dim3(D / 64, F / 64), blk, 0, stream>>>(W3, W3T, D, F);
    transpose_w<<<dim3(F / 64, D / 64), blk, 0, stream>>>(W2, W2T, F, D);

    rmsnorm_kernel<<<M, blk, 0, stream>>>(x, n1w, xn, D);
    gemm_bt<0, false, false><<<dim3(M / BM, D / BN), blk, 0, stream>>>(xn, WqT, nullptr, qtmp, M, D, D);
    gemm_bt<1, false, false><<<dim3(M / BM, D / BN), blk, 0, stream>>>(qtmp, WcT, qtmp, qfin, M, D, D);
    gemm_bt<0, false, false><<<dim3(M / BM, KVD / BN), blk, 0, stream>>>(xn, WkT, nullptr, kbuf, M, KVD, D);
    // V projection stored transposed: vbufT[d][token]
    gemm_bt<0, false, false, true><<<dim3(M / BM, KVD / BN), blk, 0, stream>>>(xn, WvT, nullptr, vbufT, M, KVD, D);
    attn_kernel<<<dim3(T / QB, 16, B), blk, 0, stream>>>(qfin, kbuf, vbufT, qtmp, T);
    gemm_bt<1, true, true><<<dim3(M / BM, D / BN), blk, 0, stream>>>(qtmp, WoT, x, x2f, M, D, D);
    rmsnorm_kernel<<<M, blk, 0, stream>>>(x2f, n2w, xn, D);
    gemm_bt<0, false, false><<<dim3(M / BM, F / BN), blk, 0, stream>>>(xn, W1T, nullptr, h1, M, F, D);
    gemm_bt<2, false, false><<<dim3(M / BM, F / BN), blk, 0, stream>>>(xn, W3T, h1, h1, M, F, D);
    gemm_bt<1, true, true><<<dim3(M / BM, D / BN), blk, 0, stream>>>(h1, W2T, x2f, out, M, D, F);
}

// Round 5
// 1104.971 us; speedup vs baseline: 2.5448x; 1.0222x over previous
//
#include <hip/hip_runtime.h>
#include <hip/hip_bf16.h>

typedef __attribute__((ext_vector_type(8))) short short8;
typedef __attribute__((ext_vector_type(4))) float floatx4;
typedef unsigned short ushort_t;

__device__ inline float b2f(ushort_t s) {
    return __uint_as_float(((unsigned int)s) << 16);
}
__device__ inline ushort_t f2b(float f) {
    unsigned int u = __float_as_uint(f);
    unsigned int r = 0x7fff + ((u >> 16) & 1);
    return (ushort_t)((u + r) >> 16);
}
__device__ inline void load8(const float* p, float* f) {
    float4 a = *(const float4*)p;
    float4 b = *(const float4*)(p + 4);
    f[0] = a.x; f[1] = a.y; f[2] = a.z; f[3] = a.w;
    f[4] = b.x; f[5] = b.y; f[6] = b.z; f[7] = b.w;
}
__device__ inline void gload16(const ushort_t* g, ushort_t* l) {
    __builtin_amdgcn_global_load_lds(
        (const __attribute__((address_space(1))) unsigned int*)g,
        (__attribute__((address_space(3))) unsigned int*)l, 16, 0, 0);
}

// ---------- weight pre-pass: fp32 [K,N] -> bf16 [N,K] ----------
__global__ __launch_bounds__(256) void transpose_w(const float* __restrict__ src,
                                                   ushort_t* __restrict__ dst,
                                                   int K, int N) {
    __shared__ ushort_t tile[64][65];
    int kb = blockIdx.x * 64, nb = blockIdx.y * 64;
    int t = threadIdx.x;
#pragma unroll
    for (int i = 0; i < 4; ++i) {
        int r = (t >> 4) + i * 16;
        int c = (t & 15) * 4;
        float4 v = *(const float4*)(src + (size_t)(kb + r) * N + nb + c);
        tile[c + 0][r] = f2b(v.x);
        tile[c + 1][r] = f2b(v.y);
        tile[c + 2][r] = f2b(v.z);
        tile[c + 3][r] = f2b(v.w);
    }
    __syncthreads();
#pragma unroll
    for (int i = 0; i < 2; ++i) {
        int s = t + i * 256;
        int n = s >> 3, kc = (s & 7) * 8;
        ushort_t o[8];
#pragma unroll
        for (int j = 0; j < 8; ++j) o[j] = tile[n][kc + j];
        *(uint4*)(dst + (size_t)(nb + n) * K + kb + kc) = *(const uint4*)o;
    }
}

// ---------------- RMSNorm: fp32 in -> bf16 out ----------------
__global__ __launch_bounds__(256) void rmsnorm_kernel(const float* __restrict__ x,
                                                      const float* __restrict__ w,
                                                      ushort_t* __restrict__ out, int D) {
    int row = blockIdx.x;
    int t = threadIdx.x;
    const float* xr = x + (size_t)row * D;
    float f[8];
    load8(xr + t * 8, f);
    float ss = 0.f;
#pragma unroll
    for (int i = 0; i < 8; ++i) ss += f[i] * f[i];
#pragma unroll
    for (int m = 1; m < 64; m <<= 1) ss += __shfl_xor(ss, m);
    __shared__ float wsum[4];
    if ((t & 63) == 0) wsum[t >> 6] = ss;
    __syncthreads();
    float tot = wsum[0] + wsum[1] + wsum[2] + wsum[3];
    float r = rsqrtf(tot / (float)D + 1e-6f);
    float wf[8];
    load8(w + t * 8, wf);
    ushort_t o[8];
#pragma unroll
    for (int i = 0; i < 8; ++i) o[i] = f2b(f[i] * r * wf[i]);
    *(uint4*)(out + (size_t)row * D + t * 8) = *(const uint4*)o;
}

// ---------------- m97-structure GEMM: C[M,N] = A[M,K](bf16) * Bt[N,K](bf16) ----------------
#define BM 128
#define BN 128
#define BK 32

template <int MODE, bool AUXF, bool OUTF, bool OUTT = false>
__global__ __launch_bounds__(256, 2) void gemm_bt(const ushort_t* __restrict__ A,
                                                  const ushort_t* __restrict__ Bt,
                                                  const void* __restrict__ AUXv,
                                                  void* __restrict__ Cv,
                                                  int M, int N, int K) {
    __shared__ __align__(16) ushort_t As[BM * BK];
    __shared__ __align__(16) ushort_t Bs[BN * BK];
    int t = threadIdx.x, wave = t >> 6, lane = t & 63;
    int l16 = lane & 15, l4 = lane >> 4;
    int bm = blockIdx.x * BM, bn = blockIdx.y * BN;
    int wm = (wave >> 1) * 64, wn = (wave & 1) * 64;
    floatx4 acc[4][4] = {};
    const ushort_t* gA = A + (size_t)(bm + wave * 32 + (lane >> 2)) * K + (lane & 3) * 8;
    const ushort_t* gB = Bt + (size_t)(bn + wave * 32 + (lane >> 2)) * K + (lane & 3) * 8;
    ushort_t* lA = As + wave * 32 * BK;
    ushort_t* lB = Bs + wave * 32 * BK;
    int ktiles = K / BK;
    for (int kt = 0; kt < ktiles; ++kt) {
        __syncthreads();
        int k0 = kt * BK;
        gload16(gA + k0, lA);
        gload16(gA + 16 * K + k0, lA + 16 * BK);
        gload16(gB + k0, lB);
        gload16(gB + 16 * K + k0, lB + 16 * BK);
        __syncthreads();
        short8 af[4], bf[4];
#pragma unroll
        for (int i = 0; i < 4; ++i)
            af[i] = *(const short8*)(As + (wm + i * 16 + l16) * BK + l4 * 8);
#pragma unroll
        for (int i = 0; i < 4; ++i)
            bf[i] = *(const short8*)(Bs + (wn + i * 16 + l16) * BK + l4 * 8);
#pragma unroll
        for (int mi = 0; mi < 4; ++mi)
#pragma unroll
            for (int ni = 0; ni < 4; ++ni)
                acc[mi][ni] = __builtin_amdgcn_mfma_f32_16x16x32_bf16(af[mi], bf[ni], acc[mi][ni], 0, 0, 0);
    }
#pragma unroll
    for (int mi = 0; mi < 4; ++mi)
#pragma unroll
        for (int ni = 0; ni < 4; ++ni)
#pragma unroll
            for (int r = 0; r < 4; ++r) {
                int row = bm + wm + mi * 16 + l4 * 4 + r;
                int col = bn + wn + ni * 16 + l16;
                size_t idx = (size_t)row * N + col;
                float v = acc[mi][ni][r];
                if (MODE == 1) {
                    float a = AUXF ? ((const float*)AUXv)[idx] : b2f(((const ushort_t*)AUXv)[idx]);
                    v += a;
                }
                if (MODE == 2) {
                    float h = AUXF ? ((const float*)AUXv)[idx] : b2f(((const ushort_t*)AUXv)[idx]);
                    v = (h / (1.f + __expf(-h))) * v;
                }
                if (OUTT) ((ushort_t*)Cv)[(size_t)col * M + row] = f2b(v);
                else if (OUTF) ((float*)Cv)[idx] = v;
                else ((ushort_t*)Cv)[idx] = f2b(v);
            }
}

// ---------------- fused MLP GEMM: h = silu(A*W1t) * (A*W3t), same tile staged once ----------------
__global__ __launch_bounds__(256, 2) void gemm_dual(const ushort_t* __restrict__ A,
                                                    const ushort_t* __restrict__ B1t,
                                                    const ushort_t* __restrict__ B3t,
                                                    ushort_t* __restrict__ C,
                                                    int M, int N, int K) {
    __shared__ __align__(16) ushort_t As[BM * BK];
    __shared__ __align__(16) ushort_t Bs1[BN * BK];
    __shared__ __align__(16) ushort_t Bs3[BN * BK];
    int t = threadIdx.x, wave = t >> 6, lane = t & 63;
    int l16 = lane & 15, l4 = lane >> 4;
    int bm = blockIdx.x * BM, bn = blockIdx.y * BN;
    int wm = (wave >> 1) * 64, wn = (wave & 1) * 64;
    floatx4 acc1[4][4] = {}, acc3[4][4] = {};
    const ushort_t* gA = A + (size_t)(bm + wave * 32 + (lane >> 2)) * K + (lane & 3) * 8;
    const ushort_t* gB1 = B1t + (size_t)(bn + wave * 32 + (lane >> 2)) * K + (lane & 3) * 8;
    const ushort_t* gB3 = B3t + (size_t)(bn + wave * 32 + (lane >> 2)) * K + (lane & 3) * 8;
    ushort_t* lA = As + wave * 32 * BK;
    ushort_t* lB1 = Bs1 + wave * 32 * BK;
    ushort_t* lB3 = Bs3 + wave * 32 * BK;
    int ktiles = K / BK;
    for (int kt = 0; kt < ktiles; ++kt) {
        __syncthreads();
        int k0 = kt * BK;
        gload16(gA + k0, lA);
        gload16(gA + 16 * K + k0, lA + 16 * BK);
        gload16(gB1 + k0, lB1);
        gload16(gB1 + 16 * K + k0, lB1 + 16 * BK);
        gload16(gB3 + k0, lB3);
        gload16(gB3 + 16 * K + k0, lB3 + 16 * BK);
        __syncthreads();
        short8 af[4], b1[4], b3[4];
#pragma unroll
        for (int i = 0; i < 4; ++i)
            af[i] = *(const short8*)(As + (wm + i * 16 + l16) * BK + l4 * 8);
#pragma unroll
        for (int i = 0; i < 4; ++i) {
            b1[i] = *(const short8*)(Bs1 + (wn + i * 16 + l16) * BK + l4 * 8);
            b3[i] = *(const short8*)(Bs3 + (wn + i * 16 + l16) * BK + l4 * 8);
        }
        __builtin_amdgcn_s_setprio(1);
#pragma unroll
        for (int mi = 0; mi < 4; ++mi)
#pragma unroll
            for (int ni = 0; ni < 4; ++ni) {
                acc1[mi][ni] = __builtin_amdgcn_mfma_f32_16x16x32_bf16(af[mi], b1[ni], acc1[mi][ni], 0, 0, 0);
                acc3[mi][ni] = __builtin_amdgcn_mfma_f32_16x16x32_bf16(af[mi], b3[ni], acc3[mi][ni], 0, 0, 0);
            }
        __builtin_amdgcn_s_setprio(0);
    }
#pragma unroll
    for (int mi = 0; mi < 4; ++mi)
#pragma unroll
        for (int ni = 0; ni < 4; ++ni)
#pragma unroll
            for (int r = 0; r < 4; ++r) {
                int row = bm + wm + mi * 16 + l4 * 4 + r;
                int col = bn + wn + ni * 16 + l16;
                float h = acc1[mi][ni][r];
                float v = (h / (1.f + __expf(-h))) * acc3[mi][ni][r];
                C[(size_t)row * N + col] = f2b(v);
            }
}

// ---------------- Flash attention (causal, GQA) ----------------
// grid: (T/128, N_HEADS, B). block 256 = 4 waves; wave owns 32 q rows (2 frags). SB=64.
#define QB 128
#define SB 64

__global__ __launch_bounds__(256, 2) void attn_kernel(const ushort_t* __restrict__ Q,
                                                      const ushort_t* __restrict__ Kb,
                                                      const ushort_t* __restrict__ VbT,
                                                      ushort_t* __restrict__ O, int Tlen) {
    const int D = 2048, KVD = 512, dh = 128;
    const int MTOK = 4096;
    int qt = blockIdx.x, h = blockIdx.y, b = blockIdx.z;
    int kv = h >> 2;
    int t = threadIdx.x, wave = t >> 6, lane = t & 63;
    int l16 = lane & 15, l4 = lane >> 4;
    __shared__ __align__(16) ushort_t Ks[SB][dh + 8];      // [s][d]  17.4 KB
    __shared__ __align__(16) ushort_t Vt[dh][SB + 8];      // [d][s]  18.4 KB
    __shared__ __align__(16) ushort_t Ps[8][16][SB + 8];   // 18.4 KB
    int qbase = qt * QB;
    int qfrag = qbase + wave * 32;
    short8 qf[2][4];
#pragma unroll
    for (int f = 0; f < 2; ++f) {
        const ushort_t* Qrow = Q + ((size_t)(b * Tlen) + qfrag + f * 16 + l16) * D + h * dh;
#pragma unroll
        for (int kk = 0; kk < 4; ++kk) qf[f][kk] = *(const short8*)(Qrow + kk * 32 + l4 * 8);
    }
    floatx4 o_acc[2][8] = {};
    float m_r[2][4], l_r[2][4];
#pragma unroll
    for (int f = 0; f < 2; ++f)
#pragma unroll
        for (int r = 0; r < 4; ++r) { m_r[f][r] = -INFINITY; l_r[f][r] = 0.f; }
    const float scale = 0.08838834764831845f;
    int nst = (qbase + QB) / SB;
    // staging addresses: K rows (t>>4)+p*16, cols (t&15)*8 ; V rows d=(t>>3)+p*32, s=(t&7)*8
    const ushort_t* Kg = Kb + ((size_t)(b * Tlen) + (t >> 4)) * KVD + kv * dh + (t & 15) * 8;
    const ushort_t* Vg = VbT + (size_t)(kv * dh + (t >> 3)) * MTOK + b * Tlen + (t & 7) * 8;
    uint4 kreg[4], vreg[4];
#pragma unroll
    for (int p = 0; p < 4; ++p) {
        kreg[p] = *(const uint4*)(Kg + (size_t)(p * 16) * KVD);
        vreg[p] = *(const uint4*)(Vg + (size_t)(p * 32) * MTOK);
    }
    for (int st = 0; st < nst; ++st) {
        __syncthreads();
#pragma unroll
        for (int p = 0; p < 4; ++p) {
            *(uint4*)(&Ks[(t >> 4) + p * 16][(t & 15) * 8]) = kreg[p];
            *(uint4*)(&Vt[(t >> 3) + p * 32][(t & 7) * 8]) = vreg[p];
        }
        __syncthreads();
        if (st + 1 < nst) {
            size_t off = (size_t)(st + 1) * SB;
#pragma unroll
            for (int p = 0; p < 4; ++p) {
                kreg[p] = *(const uint4*)(Kg + (off + p * 16) * KVD);
                vreg[p] = *(const uint4*)(Vg + (size_t)(p * 32) * MTOK + off);
            }
        }
        int s0 = st * SB;
        if (s0 < qfrag + 32) {
            floatx4 sa[2][4] = {};
            __builtin_amdgcn_s_setprio(1);
#pragma unroll
            for (int ss = 0; ss < 4; ++ss)
#pragma unroll
                for (int kk = 0; kk < 4; ++kk) {
                    short8 kf = *(const short8*)(&Ks[ss * 16 + l16][kk * 32 + l4 * 8]);
                    sa[0][ss] = __builtin_amdgcn_mfma_f32_16x16x32_bf16(qf[0][kk], kf, sa[0][ss], 0, 0, 0);
                    sa[1][ss] = __builtin_amdgcn_mfma_f32_16x16x32_bf16(qf[1][kk], kf, sa[1][ss], 0, 0, 0);
                }
            __builtin_amdgcn_s_setprio(0);
#pragma unroll
            for (int f = 0; f < 2; ++f) {
                float sv[4][4], pmax[4];
#pragma unroll
                for (int r = 0; r < 4; ++r) pmax[r] = -INFINITY;
#pragma unroll
                for (int ss = 0; ss < 4; ++ss) {
                    int scol = s0 + ss * 16 + l16;
#pragma unroll
                    for (int r = 0; r < 4; ++r) {
                        int qrow = qfrag + f * 16 + l4 * 4 + r;
                        float v = sa[f][ss][r] * scale;
                        if (scol > qrow) v = -INFINITY;
                        sv[ss][r] = v;
                        pmax[r] = fmaxf(pmax[r], v);
                    }
                }
#pragma unroll
                for (int m = 1; m < 16; m <<= 1)
#pragma unroll
                    for (int r = 0; r < 4; ++r) pmax[r] = fmaxf(pmax[r], __shfl_xor(pmax[r], m));
                float esc[4], rsum[4];
#pragma unroll
                for (int r = 0; r < 4; ++r) {
                    float mn = fmaxf(m_r[f][r], pmax[r]);
                    esc[r] = __expf(m_r[f][r] - mn);
                    float rs = 0.f;
#pragma unroll
                    for (int ss = 0; ss < 4; ++ss) {
                        float p = __expf(sv[ss][r] - mn);
                        sv[ss][r] = p;
                        rs += p;
                    }
                    rsum[r] = rs;
                    m_r[f][r] = mn;
                }
#pragma unroll
                for (int m = 1; m < 16; m <<= 1)
#pragma unroll
                    for (int r = 0; r < 4; ++r) rsum[r] += __shfl_xor(rsum[r], m);
#pragma unroll
                for (int r = 0; r < 4; ++r) l_r[f][r] = l_r[f][r] * esc[r] + rsum[r];
#pragma unroll
                for (int c = 0; c < 8; ++c)
#pragma unroll
                    for (int r = 0; r < 4; ++r) o_acc[f][c][r] *= esc[r];
#pragma unroll
                for (int ss = 0; ss < 4; ++ss)
#pragma unroll
                    for (int r = 0; r < 4; ++r)
                        Ps[wave * 2 + f][l4 * 4 + r][ss * 16 + l16] = f2b(sv[ss][r]);
            }
            short8 pa[2][2];
#pragma unroll
            for (int f = 0; f < 2; ++f)
#pragma unroll
                for (int kk = 0; kk < 2; ++kk)
                    pa[f][kk] = *(const short8*)(&Ps[wave * 2 + f][l16][kk * 32 + l4 * 8]);
            __builtin_amdgcn_s_setprio(1);
#pragma unroll
            for (int c = 0; c < 8; ++c)
#pragma unroll
                for (int kk = 0; kk < 2; ++kk) {
                    short8 vf = *(const short8*)(&Vt[c * 16 + l16][kk * 32 + l4 * 8]);
                    o_acc[0][c] = __builtin_amdgcn_mfma_f32_16x16x32_bf16(pa[0][kk], vf, o_acc[0][c], 0, 0, 0);
                    o_acc[1][c] = __builtin_amdgcn_mfma_f32_16x16x32_bf16(pa[1][kk], vf, o_acc[1][c], 0, 0, 0);
                }
            __builtin_amdgcn_s_setprio(0);
        }
    }
#pragma unroll
    for (int f = 0; f < 2; ++f)
#pragma unroll
        for (int c = 0; c < 8; ++c)
#pragma unroll
            for (int r = 0; r < 4; ++r) {
                int qrow = qfrag + f * 16 + l4 * 4 + r;
                int col = h * dh + c * 16 + l16;
                O[((size_t)(b * Tlen) + qrow) * D + col] = f2b(o_acc[f][c][r] / l_r[f][r]);
            }
}

extern "C" void kernel_launch(void* const* d_in, const int* in_sizes, int n_in,
                              void* d_out, int out_size, void* d_ws, size_t ws_size,
                              hipStream_t stream) {
    const float* x   = (const float*)d_in[0];
    const float* n1w = (const float*)d_in[1];
    const float* n2w = (const float*)d_in[2];
    const float* Wq  = (const float*)d_in[3];
    const float* Wk  = (const float*)d_in[4];
    const float* Wv  = (const float*)d_in[5];
    const float* Wo  = (const float*)d_in[6];
    const float* Wc  = (const float*)d_in[7];
    const float* W1  = (const float*)d_in[8];
    const float* W2  = (const float*)d_in[9];
    const float* W3  = (const float*)d_in[10];
    float* out = (float*)d_out;

    const int B = 2, T = 2048, D = 2048, F = 8192, KVD = 512;
    const int M = B * T;  // 4096
    const size_t XD   = (size_t)M * D * 2;
    const size_t XDF  = (size_t)M * D * 4;
    const size_t KVSZ = (size_t)M * KVD * 2;
    const size_t MF   = (size_t)M * F * 2;
    const size_t WDD  = (size_t)D * D * 2;
    const size_t WDK  = (size_t)D * KVD * 2;
    const size_t WDF  = (size_t)D * F * 2;

    char* w = (char*)d_ws;
    ushort_t* xn    = (ushort_t*)(w);
    ushort_t* qtmp  = (ushort_t*)(w + XD);
    ushort_t* qfin  = (ushort_t*)(w + 2 * XD);
    float*    x2f   = (float*)   (w + 3 * XD);
    ushort_t* kbuf  = (ushort_t*)(w + 3 * XD + XDF);
    ushort_t* vbufT = (ushort_t*)(w + 3 * XD + XDF + KVSZ);
    ushort_t* h1    = (ushort_t*)(w + 3 * XD + XDF + 2 * KVSZ);
    char* wt = w + 3 * XD + XDF + 2 * KVSZ + MF;
    ushort_t* WqT = (ushort_t*)(wt);
    ushort_t* WcT = (ushort_t*)(wt + WDD);
    ushort_t* WoT = (ushort_t*)(wt + 2 * WDD);
    ushort_t* WkT = (ushort_t*)(wt + 3 * WDD);
    ushort_t* WvT = (ushort_t*)(wt + 3 * WDD + WDK);
    ushort_t* W1T = (ushort_t*)(wt + 3 * WDD + 2 * WDK);
    ushort_t* W3T = (ushort_t*)(wt + 3 * WDD + 2 * WDK + WDF);
    ushort_t* W2T = (ushort_t*)(wt + 3 * WDD + 2 * WDK + 2 * WDF);

    dim3 blk(256);

    transpose_w<<<dim3(D / 64, D / 64), blk, 0, stream>>>(Wq, WqT, D, D);
    transpose_w<<<dim3(D / 64, D / 64), blk, 0, stream>>>(Wc, WcT, D, D);
    transpose_w<<<dim3(D / 64, D / 64), blk, 0, stream>>>(Wo, WoT, D, D);
    transpose_w<<<dim3(D / 64, KVD / 64), blk, 0, stream>>>(Wk, WkT, D, KVD);
    transpose_w<<<dim3(D / 64, KVD / 64), blk, 0, stream>>>(Wv, WvT, D, KVD);
    transpose_w<<<dim3(D / 64, F / 64), blk, 0, stream>>>(W1, W1T, D, F);
    transpose_w<<<dim3(D / 64, F / 64), blk, 0, stream>>>(W3, W3T, D, F);
    transpose_w<<<dim3(F / 64, D / 64), blk, 0, stream>>>(W2, W2T, F, D);

    rmsnorm_kernel<<<M, blk, 0, stream>>>(x, n1w, xn, D);
    gemm_bt<0, false, false><<<dim3(M / BM, D / BN), blk, 0, stream>>>(xn, WqT, nullptr, qtmp, M, D, D);
    gemm_bt<1, false, false><<<dim3(M / BM, D / BN), blk, 0, stream>>>(qtmp, WcT, qtmp, qfin, M, D, D);
    gemm_bt<0, false, false><<<dim3(M / BM, KVD / BN), blk, 0, stream>>>(xn, WkT, nullptr, kbuf, M, KVD, D);
    gemm_bt<0, false, false, true><<<dim3(M / BM, KVD / BN), blk, 0, stream>>>(xn, WvT, nullptr, vbufT, M, KVD, D);
    attn_kernel<<<dim3(T / QB, 16, B), blk, 0, stream>>>(qfin, kbuf, vbufT, qtmp, T);
    gemm_bt<1, true, true><<<dim3(M / BM, D / BN), blk, 0, stream>>>(qtmp, WoT, x, x2f, M, D, D);
    rmsnorm_kernel<<<M, blk, 0, stream>>>(x2f, n2w, xn, D);
    // fused MLP: h1 = silu(xn2 @ W1) * (xn2 @ W3)
    gemm_dual<<<dim3(M / BM, F / BN), blk, 0, stream>>>(xn, W1T, W3T, h1, M, F, D);
    gemm_bt<1, true, true><<<dim3(M / BM, D / BN), blk, 0, stream>>>(h1, W2T, x2f, out, M, D, F);
}